// Round 12
// baseline (311.830 us; speedup 1.0000x reference)
//
#include <hip/hip_runtime.h>
#include <math.h>
#include <stdint.h>

typedef unsigned short u16;
typedef __bf16 bf16x8 __attribute__((ext_vector_type(8)));
typedef unsigned short u16x8 __attribute__((ext_vector_type(8)));
typedef float f32x4 __attribute__((ext_vector_type(4)));

constexpr int Tc = 2048, Dc = 1024, Hc = 16, Mc = 8192;
constexpr size_t NQKV = (size_t)Mc * Dc;   // 8388608
constexpr size_t NW = (size_t)Dc * Dc;     // 1048576

__device__ __forceinline__ u16 f2bf(float f) {
    union { float f; uint32_t u; } c; c.f = f;
    uint32_t u = c.u;
    u += 0x7FFFu + ((u >> 16) & 1u);       // RNE
    return (u16)(u >> 16);
}

__device__ __forceinline__ bf16x8 ldbf8(const u16* p) {
    u16x8 v = *(const u16x8*)p;
    return __builtin_bit_cast(bf16x8, v);
}

__device__ __forceinline__ float fexp2(float x) {
#if __has_builtin(__builtin_amdgcn_exp2f)
    return __builtin_amdgcn_exp2f(x);
#else
    return exp2f(x);
#endif
}

// global->LDS direct copy, 16B per lane. LDS dest is wave-uniform base;
// lane i lands at base + i*16B.
__device__ __forceinline__ void gload_lds16(const void* g, void* l) {
    __builtin_amdgcn_global_load_lds(
        (__attribute__((address_space(1))) void*)(uintptr_t)g,
        (__attribute__((address_space(3))) void*)l, 16, 0, 0);
}

// ---------------------------------------------------------------------------
// fp32 -> bf16 convert of x (8192x1024), 4 elems/thread
// ---------------------------------------------------------------------------
__global__ __launch_bounds__(256)
void cvt_x_kernel(const float* __restrict__ x, u16* __restrict__ xb)
{
    int i = blockIdx.x * 256 + threadIdx.x;        // float4 index
    float4 v = ((const float4*)x)[i];
    ushort4 o;
    o.x = f2bf(v.x); o.y = f2bf(v.y); o.z = f2bf(v.z); o.w = f2bf(v.w);
    ((ushort4*)xb)[i] = o;
}

// ---------------------------------------------------------------------------
// Weight transpose+convert: WT[n][k] = bf16(W[k][n]), for Wq,Wk,Wv,Wo (z)
// ---------------------------------------------------------------------------
__global__ __launch_bounds__(256)
void wt_cvt_kernel(const float* __restrict__ Wq, const float* __restrict__ Wk,
                   const float* __restrict__ Wv, const float* __restrict__ Wo,
                   u16* __restrict__ WTq, u16* __restrict__ WTk,
                   u16* __restrict__ WTv, u16* __restrict__ WTo)
{
    __shared__ float Ts[64][65];
    const int z = blockIdx.z;
    const float* W = (z == 0) ? Wq : (z == 1) ? Wk : (z == 2) ? Wv : Wo;
    u16* WT        = (z == 0) ? WTq : (z == 1) ? WTk : (z == 2) ? WTv : WTo;
    const int k0 = blockIdx.x * 64, n0 = blockIdx.y * 64;
    const int tid = threadIdx.x;
    #pragma unroll
    for (int it = 0; it < 16; ++it) {
        int flat = it * 256 + tid;
        int r = flat >> 6, c = flat & 63;
        Ts[r][c] = W[(size_t)(k0 + r) * Dc + n0 + c];
    }
    __syncthreads();
    #pragma unroll
    for (int it = 0; it < 16; ++it) {
        int flat = it * 256 + tid;
        int rn = flat >> 6, ck = flat & 63;
        WT[(size_t)(n0 + rn) * Dc + k0 + ck] = f2bf(Ts[ck][rn]);
    }
}

// ---------------------------------------------------------------------------
// bf16 MFMA GEMM (m97 structure): C[8192][1024] = A[8192][1024] x BT[1024][1024]^T
// 128x128 tile, BK=32, 4 waves (2x2), each wave 64x64 = 4x4 frags of 16x16x32.
// QKV variant: bf16 output permuted to [B*H][T][64]; Q scaled by 0.125*log2e
// (softmax runs in exp2 domain downstream).
// ---------------------------------------------------------------------------
__global__ __launch_bounds__(256)
void qkv_gemm_kernel(const u16* __restrict__ xb,
                     const u16* __restrict__ WTq, const u16* __restrict__ WTk,
                     const u16* __restrict__ WTv,
                     u16* __restrict__ Qb, u16* __restrict__ Kb, u16* __restrict__ Vb)
{
    const int z = blockIdx.z;
    const u16* WT = (z == 0) ? WTq : (z == 1) ? WTk : WTv;
    u16* outp     = (z == 0) ? Qb  : (z == 1) ? Kb  : Vb;
    const float scale = (z == 0) ? 0.125f * 1.44269504088896f : 1.0f;

    __shared__ __align__(16) u16 As[128 * 32];
    __shared__ __align__(16) u16 Bs[128 * 32];

    const int tid = threadIdx.x, lane = tid & 63, w = tid >> 6;
    const int wm = w >> 1, wn = w & 1;
    const int m0 = blockIdx.x * 128, n0 = blockIdx.y * 128;

    f32x4 acc[4][4] = {};

    for (int k0 = 0; k0 < Dc; k0 += 32) {
        __syncthreads();
        #pragma unroll
        for (int t = 0; t < 2; ++t) {
            int ci = w * 64 + t * 256 + lane;          // 16B chunk id, 512 total
            int r = ci >> 2, p = ci & 3;               // row, chunk-in-row
            int pc = p ^ ((r >> 1) & 3);               // source pre-swizzle
            gload_lds16(xb + (size_t)(m0 + r) * Dc + k0 + pc * 8,
                        As + (size_t)(w * 64 + t * 256) * 8);
            gload_lds16(WT + (size_t)(n0 + r) * Dc + k0 + pc * 8,
                        Bs + (size_t)(w * 64 + t * 256) * 8);
        }
        __syncthreads();   // drains vmcnt before barrier

        bf16x8 a[4], b[4];
        #pragma unroll
        for (int i = 0; i < 4; ++i) {
            int row = wm * 64 + i * 16 + (lane & 15);
            a[i] = ldbf8(As + row * 32 + (((lane >> 4) ^ ((row >> 1) & 3)) * 8));
            int col = wn * 64 + i * 16 + (lane & 15);
            b[i] = ldbf8(Bs + col * 32 + (((lane >> 4) ^ ((col >> 1) & 3)) * 8));
        }
        #pragma unroll
        for (int i = 0; i < 4; ++i)
            #pragma unroll
            for (int j = 0; j < 4; ++j)
                acc[i][j] = __builtin_amdgcn_mfma_f32_16x16x32_bf16(a[i], b[j], acc[i][j], 0, 0, 0);
    }

    // Epilogue: permuted bf16 store to [B*H][T][64]
    #pragma unroll
    for (int j = 0; j < 4; ++j) {
        int n = n0 + wn * 64 + j * 16 + (lane & 15);
        int hh = n >> 6, dh = n & 63;
        #pragma unroll
        for (int i = 0; i < 4; ++i) {
            #pragma unroll
            for (int r = 0; r < 4; ++r) {
                int m = m0 + wm * 64 + i * 16 + (lane >> 4) * 4 + r;
                int bb = m >> 11, t = m & 2047;
                outp[((size_t)(bb * Hc + hh) * Tc + t) * 64 + dh] = f2bf(acc[i][j][r] * scale);
            }
        }
    }
}

// ---------------------------------------------------------------------------
// V transpose per bh: VT[bh][d][t] = V[bh][t][d]
// ---------------------------------------------------------------------------
__global__ __launch_bounds__(256)
void v_transpose_kernel(const u16* __restrict__ Vb, u16* __restrict__ VTb)
{
    __shared__ u16 Ts[64][68];
    const int tid = threadIdx.x;
    const int bh = blockIdx.y, t0 = blockIdx.x * 64;
    const size_t vbase = (size_t)bh * Tc * 64;
    #pragma unroll
    for (int it = 0; it < 4; ++it) {
        int flat = it * 1024 + tid * 4;
        int r = flat >> 6, c = flat & 63;
        *(ushort4*)&Ts[r][c] = *(const ushort4*)(Vb + vbase + (size_t)(t0 + r) * 64 + c);
    }
    __syncthreads();
    const size_t obase = (size_t)bh * 64 * Tc;
    #pragma unroll
    for (int it = 0; it < 4; ++it) {
        int flat = it * 1024 + tid * 4;
        int d = flat >> 6, tl = flat & 63;
        ushort4 o;
        o.x = Ts[tl][d]; o.y = Ts[tl + 1][d]; o.z = Ts[tl + 2][d]; o.w = Ts[tl + 3][d];
        *(ushort4*)(VTb + obase + (size_t)d * Tc + t0 + tl) = o;
    }
}

// ---------------------------------------------------------------------------
// MFMA flash attention (causal), BARRIER-FREE: each wave is an independent
// 32-q-row flash attention; K/V fragments loaded directly global->VGPR
// (L2-resident: 8 bh per XCD = 4 MB). No shared K/V LDS, zero __syncthreads.
// Per-instr K/V load pattern = 16 rows x 64 contiguous B (clean 64B segments).
// Swapped S^T = mfma(K,Q); exp2-domain softmax + defer-max; P transposed
// through per-wave LDS (same-wave lgkmcnt ordering). Balanced q-pairing.
// ---------------------------------------------------------------------------
__global__ __launch_bounds__(256)
void attn_mfma_kernel(const u16* __restrict__ Qb, const u16* __restrict__ Kb,
                      const u16* __restrict__ VTb, u16* __restrict__ ctxb)
{
    __shared__ __align__(16) u16 Ps[4][32 * 72];   // per-wave [q 0..31][kv 0..63] stride 72

    const int tid = threadIdx.x, lane = tid & 63, w = tid >> 6;
    const int g = lane >> 4, lq = lane & 15;
    const int p_idx = blockIdx.y & 7;
    const int bh = (blockIdx.x << 3) | (blockIdx.y >> 3);  // 8 bh per XCD
    const size_t qkbase = (size_t)bh * Tc * 64;
    const size_t vtbase = (size_t)bh * 64 * Tc;
    const int b = bh >> 4, h = bh & 15;
    u16* pw = &Ps[w][0];

    #pragma unroll 1
    for (int pass = 0; pass < 2; ++pass) {
        const int qt = pass ? (15 - p_idx) : p_idx;
        const int q0 = qt * 128 + w * 32;          // this wave's 32-row q base
        const int nkt = (q0 >> 6) + 1;             // 64-wide kv tiles for this wave

        // Q fragments (B-operand: col=q=lq, k=dh), pre-scaled by 0.125*log2e
        bf16x8 qf[2][2];
        #pragma unroll
        for (int qfi = 0; qfi < 2; ++qfi)
            #pragma unroll
            for (int kf = 0; kf < 2; ++kf) {
                int row = q0 + qfi * 16 + lq;
                qf[qfi][kf] = ldbf8(Qb + qkbase + (size_t)row * 64 + kf * 32 + g * 8);
            }

        f32x4 o_acc[2][4] = {};
        float m_run[2] = {-INFINITY, -INFINITY};
        float l_run[2] = {0.f, 0.f};

        #pragma unroll 1
        for (int kt = 0; kt < nkt; ++kt) {
            const int kv0 = kt * 64;

            // S^T = K Q^T: D[kv][q]; K fragments direct from global (L2)
            f32x4 s[4][2] = {};
            #pragma unroll
            for (int kf = 0; kf < 2; ++kf) {
                bf16x8 kb[4];
                #pragma unroll
                for (int ni = 0; ni < 4; ++ni)
                    kb[ni] = ldbf8(Kb + qkbase + (size_t)(kv0 + ni * 16 + lq) * 64 + kf * 32 + g * 8);
                __builtin_amdgcn_s_setprio(1);
                #pragma unroll
                for (int ni = 0; ni < 4; ++ni)
                    #pragma unroll
                    for (int qfi = 0; qfi < 2; ++qfi)
                        s[ni][qfi] = __builtin_amdgcn_mfma_f32_16x16x32_bf16(kb[ni], qf[qfi][kf], s[ni][qfi], 0, 0, 0);
                __builtin_amdgcn_s_setprio(0);
            }

            // causal mask: only the last tile straddles this wave's diagonal
            if (kt == nkt - 1) {
                #pragma unroll
                for (int ni = 0; ni < 4; ++ni)
                    #pragma unroll
                    for (int qfi = 0; qfi < 2; ++qfi)
                        #pragma unroll
                        for (int r = 0; r < 4; ++r) {
                            int kv = kv0 + ni * 16 + 4 * g + r;
                            int q  = q0 + qfi * 16 + lq;
                            if (kv > q) s[ni][qfi][r] = -INFINITY;
                        }
            }

            // online softmax (exp2 domain); defer-max: skip rescale if growth <= 12
            #pragma unroll
            for (int qfi = 0; qfi < 2; ++qfi) {
                float mrow = -INFINITY;
                #pragma unroll
                for (int ni = 0; ni < 4; ++ni)
                    #pragma unroll
                    for (int r = 0; r < 4; ++r) mrow = fmaxf(mrow, s[ni][qfi][r]);
                mrow = fmaxf(mrow, __shfl_xor(mrow, 16, 64));
                mrow = fmaxf(mrow, __shfl_xor(mrow, 32, 64));
                if (!__all(mrow <= m_run[qfi] + 12.0f)) {
                    float mnew  = fmaxf(m_run[qfi], mrow);
                    float alpha = fexp2(m_run[qfi] - mnew);   // exp2(-inf)=0 first tile
                    m_run[qfi] = mnew;
                    l_run[qfi] *= alpha;
                    #pragma unroll
                    for (int r = 0; r < 4; ++r) {
                        float ar = __shfl(alpha, 4 * g + r, 16);
                        #pragma unroll
                        for (int nd = 0; nd < 4; ++nd) o_acc[qfi][nd][r] *= ar;
                    }
                }
                float mq = m_run[qfi];
                float sum = 0.f;
                #pragma unroll
                for (int ni = 0; ni < 4; ++ni)
                    #pragma unroll
                    for (int r = 0; r < 4; ++r) {
                        float pe = fexp2(s[ni][qfi][r] - mq);
                        s[ni][qfi][r] = pe;
                        sum += pe;
                    }
                sum += __shfl_xor(sum, 16, 64);
                sum += __shfl_xor(sum, 32, 64);
                l_run[qfi] += sum;
            }

            // pack P -> per-wave LDS: row q_local, cols kv (stride 72 u16)
            #pragma unroll
            for (int qfi = 0; qfi < 2; ++qfi)
                #pragma unroll
                for (int ni = 0; ni < 4; ++ni) {
                    float a0 = s[ni][qfi][0], a1 = s[ni][qfi][1];
                    float a2 = s[ni][qfi][2], a3 = s[ni][qfi][3];
                    uint32_t lo, hi;
                    asm volatile("v_cvt_pk_bf16_f32 %0, %1, %2" : "=v"(lo) : "v"(a0), "v"(a1));
                    asm volatile("v_cvt_pk_bf16_f32 %0, %1, %2" : "=v"(hi) : "v"(a2), "v"(a3));
                    uint2 pk = make_uint2(lo, hi);
                    *(uint2*)(pw + (qfi * 16 + lq) * 72 + ni * 16 + 4 * g) = pk;
                }

            // PV: o[q][dh] += P[q][kv] V[kv][dh]; A=P from LDS, B=VT from global
            bf16x8 pa[2][2];
            #pragma unroll
            for (int qfi = 0; qfi < 2; ++qfi)
                #pragma unroll
                for (int kf = 0; kf < 2; ++kf)
                    pa[qfi][kf] = ldbf8(pw + (qfi * 16 + lq) * 72 + kf * 32 + 8 * g);
            #pragma unroll
            for (int kf = 0; kf < 2; ++kf) {
                bf16x8 vb[4];
                #pragma unroll
                for (int nd = 0; nd < 4; ++nd)
                    vb[nd] = ldbf8(VTb + vtbase + (size_t)(nd * 16 + lq) * Tc + kv0 + kf * 32 + g * 8);
                __builtin_amdgcn_s_setprio(1);
                #pragma unroll
                for (int qfi = 0; qfi < 2; ++qfi)
                    #pragma unroll
                    for (int nd = 0; nd < 4; ++nd)
                        o_acc[qfi][nd] = __builtin_amdgcn_mfma_f32_16x16x32_bf16(pa[qfi][kf], vb[nd], o_acc[qfi][nd], 0, 0, 0);
                __builtin_amdgcn_s_setprio(0);
            }
        }

        // normalize + store ctx [B][T][D] bf16 (l held at lane lq==q)
        #pragma unroll
        for (int qfi = 0; qfi < 2; ++qfi)
            #pragma unroll
            for (int r = 0; r < 4; ++r) {
                float lr = __shfl(l_run[qfi], 4 * g + r, 16);
                float inv = 1.0f / lr;
                int qrow = q0 + qfi * 16 + 4 * g + r;
                #pragma unroll
                for (int nd = 0; nd < 4; ++nd) {
                    int d = h * 64 + nd * 16 + lq;
                    ctxb[(size_t)(b * Tc + qrow) * Dc + d] = f2bf(o_acc[qfi][nd][r] * inv);
                }
            }
    }
}

// ---------------------------------------------------------------------------
// Output projection: out[8192][1024] = ctx @ Wo + bo   (f32 out)
// ---------------------------------------------------------------------------
__global__ __launch_bounds__(256)
void out_gemm_kernel(const u16* __restrict__ ctxb, const u16* __restrict__ WTo,
                     const float* __restrict__ bo, float* __restrict__ out)
{
    __shared__ __align__(16) u16 As[128 * 32];
    __shared__ __align__(16) u16 Bs[128 * 32];

    const int tid = threadIdx.x, lane = tid & 63, w = tid >> 6;
    const int wm = w >> 1, wn = w & 1;
    const int m0 = blockIdx.x * 128, n0 = blockIdx.y * 128;

    f32x4 acc[4][4] = {};

    for (int k0 = 0; k0 < Dc; k0 += 32) {
        __syncthreads();
        #pragma unroll
        for (int t = 0; t < 2; ++t) {
            int ci = w * 64 + t * 256 + lane;
            int r = ci >> 2, p = ci & 3;
            int pc = p ^ ((r >> 1) & 3);
            gload_lds16(ctxb + (size_t)(m0 + r) * Dc + k0 + pc * 8,
                        As + (size_t)(w * 64 + t * 256) * 8);
            gload_lds16(WTo + (size_t)(n0 + r) * Dc + k0 + pc * 8,
                        Bs + (size_t)(w * 64 + t * 256) * 8);
        }
        __syncthreads();

        bf16x8 a[4], b[4];
        #pragma unroll
        for (int i = 0; i < 4; ++i) {
            int row = wm * 64 + i * 16 + (lane & 15);
            a[i] = ldbf8(As + row * 32 + (((lane >> 4) ^ ((row >> 1) & 3)) * 8));
            int col = wn * 64 + i * 16 + (lane & 15);
            b[i] = ldbf8(Bs + col * 32 + (((lane >> 4) ^ ((col >> 1) & 3)) * 8));
        }
        #pragma unroll
        for (int i = 0; i < 4; ++i)
            #pragma unroll
            for (int j = 0; j < 4; ++j)
                acc[i][j] = __builtin_amdgcn_mfma_f32_16x16x32_bf16(a[i], b[j], acc[i][j], 0, 0, 0);
    }

    #pragma unroll
    for (int j = 0; j < 4; ++j) {
        int n = n0 + wn * 64 + j * 16 + (lane & 15);
        float bias = bo[n];
        #pragma unroll
        for (int i = 0; i < 4; ++i) {
            #pragma unroll
            for (int r = 0; r < 4; ++r) {
                int m = m0 + wm * 64 + i * 16 + (lane >> 4) * 4 + r;
                out[(size_t)m * Dc + n] = acc[i][j][r] + bias;
            }
        }
    }
}

// ---------------------------------------------------------------------------
extern "C" void kernel_launch(void* const* d_in, const int* in_sizes, int n_in,
                              void* d_out, int out_size, void* d_ws, size_t ws_size,
                              hipStream_t stream)
{
    const float* x  = (const float*)d_in[0];
    const float* Wq = (const float*)d_in[1];
    const float* Wk = (const float*)d_in[2];
    const float* Wv = (const float*)d_in[3];
    const float* Wo = (const float*)d_in[4];
    const float* bo = (const float*)d_in[5];
    float* out = (float*)d_out;

    u16* xb   = (u16*)d_ws;            // [8192][1024]
    u16* WTq  = xb + NQKV;             // [1024][1024] (n-major)
    u16* WTk  = WTq + NW;
    u16* WTv  = WTk + NW;
    u16* WTo  = WTv + NW;
    u16* Qb   = WTo + NW;              // [BH][T][64], pre-scaled by 0.125*log2e
    u16* Kb   = Qb + NQKV;
    u16* Vb   = Kb + NQKV;
    u16* VTb  = Vb + NQKV;             // [BH][64][T]
    u16* ctxb = VTb + NQKV;            // [B][T][D]

    cvt_x_kernel<<<8192, 256, 0, stream>>>(x, xb);
    wt_cvt_kernel<<<dim3(16, 16, 4), 256, 0, stream>>>(Wq, Wk, Wv, Wo, WTq, WTk, WTv, WTo);
    qkv_gemm_kernel<<<dim3(64, 8, 3), 256, 0, stream>>>(xb, WTq, WTk, WTv, Qb, Kb, Vb);
    v_transpose_kernel<<<dim3(32, 64), 256, 0, stream>>>(Vb, VTb);
    attn_mfma_kernel<<<dim3(8, 64), 256, 0, stream>>>(Qb, Kb, VTb, ctxb);
    out_gemm_kernel<<<dim3(64, 8), 256, 0, stream>>>(ctxb, WTo, bo, out);
}

// Round 13
// 254.500 us; speedup vs baseline: 1.2253x; 1.2253x over previous
//
#include <hip/hip_runtime.h>
#include <math.h>
#include <stdint.h>

typedef unsigned short u16;
typedef __bf16 bf16x8 __attribute__((ext_vector_type(8)));
typedef unsigned short u16x8 __attribute__((ext_vector_type(8)));
typedef float f32x4 __attribute__((ext_vector_type(4)));

constexpr int Tc = 2048, Dc = 1024, Hc = 16, Mc = 8192;
constexpr size_t NQKV = (size_t)Mc * Dc;   // 8388608
constexpr size_t NW = (size_t)Dc * Dc;     // 1048576

__device__ __forceinline__ u16 f2bf(float f) {
    union { float f; uint32_t u; } c; c.f = f;
    uint32_t u = c.u;
    u += 0x7FFFu + ((u >> 16) & 1u);       // RNE
    return (u16)(u >> 16);
}

__device__ __forceinline__ bf16x8 ldbf8(const u16* p) {
    u16x8 v = *(const u16x8*)p;
    return __builtin_bit_cast(bf16x8, v);
}

__device__ __forceinline__ float fexp2(float x) {
#if __has_builtin(__builtin_amdgcn_exp2f)
    return __builtin_amdgcn_exp2f(x);
#else
    return exp2f(x);
#endif
}

// global->LDS direct copy, 16B per lane. LDS dest is wave-uniform base;
// lane i lands at base + i*16B.
__device__ __forceinline__ void gload_lds16(const void* g, void* l) {
    __builtin_amdgcn_global_load_lds(
        (__attribute__((address_space(1))) void*)(uintptr_t)g,
        (__attribute__((address_space(3))) void*)l, 16, 0, 0);
}

// ---------------------------------------------------------------------------
// fp32 -> bf16 convert of x (8192x1024), 4 elems/thread
// ---------------------------------------------------------------------------
__global__ __launch_bounds__(256)
void cvt_x_kernel(const float* __restrict__ x, u16* __restrict__ xb)
{
    int i = blockIdx.x * 256 + threadIdx.x;        // float4 index
    float4 v = ((const float4*)x)[i];
    ushort4 o;
    o.x = f2bf(v.x); o.y = f2bf(v.y); o.z = f2bf(v.z); o.w = f2bf(v.w);
    ((ushort4*)xb)[i] = o;
}

// ---------------------------------------------------------------------------
// Weight transpose+convert: WT[n][k] = bf16(W[k][n]), for Wq,Wk,Wv,Wo (z)
// ---------------------------------------------------------------------------
__global__ __launch_bounds__(256)
void wt_cvt_kernel(const float* __restrict__ Wq, const float* __restrict__ Wk,
                   const float* __restrict__ Wv, const float* __restrict__ Wo,
                   u16* __restrict__ WTq, u16* __restrict__ WTk,
                   u16* __restrict__ WTv, u16* __restrict__ WTo)
{
    __shared__ float Ts[64][65];
    const int z = blockIdx.z;
    const float* W = (z == 0) ? Wq : (z == 1) ? Wk : (z == 2) ? Wv : Wo;
    u16* WT        = (z == 0) ? WTq : (z == 1) ? WTk : (z == 2) ? WTv : WTo;
    const int k0 = blockIdx.x * 64, n0 = blockIdx.y * 64;
    const int tid = threadIdx.x;
    #pragma unroll
    for (int it = 0; it < 16; ++it) {
        int flat = it * 256 + tid;
        int r = flat >> 6, c = flat & 63;
        Ts[r][c] = W[(size_t)(k0 + r) * Dc + n0 + c];
    }
    __syncthreads();
    #pragma unroll
    for (int it = 0; it < 16; ++it) {
        int flat = it * 256 + tid;
        int rn = flat >> 6, ck = flat & 63;
        WT[(size_t)(n0 + rn) * Dc + k0 + ck] = f2bf(Ts[ck][rn]);
    }
}

// ---------------------------------------------------------------------------
// bf16 MFMA GEMM (m97 structure): C[8192][1024] = A[8192][1024] x BT[1024][1024]^T
// 128x128 tile, BK=32, 4 waves (2x2), each wave 64x64 = 4x4 frags of 16x16x32.
// QKV variant: bf16 output permuted to [B*H][T][64]; Q scaled by 0.125*log2e
// (softmax runs in exp2 domain downstream).
// ---------------------------------------------------------------------------
__global__ __launch_bounds__(256)
void qkv_gemm_kernel(const u16* __restrict__ xb,
                     const u16* __restrict__ WTq, const u16* __restrict__ WTk,
                     const u16* __restrict__ WTv,
                     u16* __restrict__ Qb, u16* __restrict__ Kb, u16* __restrict__ Vb)
{
    const int z = blockIdx.z;
    const u16* WT = (z == 0) ? WTq : (z == 1) ? WTk : WTv;
    u16* outp     = (z == 0) ? Qb  : (z == 1) ? Kb  : Vb;
    const float scale = (z == 0) ? 0.125f * 1.44269504088896f : 1.0f;

    __shared__ __align__(16) u16 As[128 * 32];
    __shared__ __align__(16) u16 Bs[128 * 32];

    const int tid = threadIdx.x, lane = tid & 63, w = tid >> 6;
    const int wm = w >> 1, wn = w & 1;
    const int m0 = blockIdx.x * 128, n0 = blockIdx.y * 128;

    f32x4 acc[4][4] = {};

    for (int k0 = 0; k0 < Dc; k0 += 32) {
        __syncthreads();
        #pragma unroll
        for (int t = 0; t < 2; ++t) {
            int ci = w * 64 + t * 256 + lane;          // 16B chunk id, 512 total
            int r = ci >> 2, p = ci & 3;               // row, chunk-in-row
            int pc = p ^ ((r >> 1) & 3);               // source pre-swizzle
            gload_lds16(xb + (size_t)(m0 + r) * Dc + k0 + pc * 8,
                        As + (size_t)(w * 64 + t * 256) * 8);
            gload_lds16(WT + (size_t)(n0 + r) * Dc + k0 + pc * 8,
                        Bs + (size_t)(w * 64 + t * 256) * 8);
        }
        __syncthreads();   // drains vmcnt before barrier

        bf16x8 a[4], b[4];
        #pragma unroll
        for (int i = 0; i < 4; ++i) {
            int row = wm * 64 + i * 16 + (lane & 15);
            a[i] = ldbf8(As + row * 32 + (((lane >> 4) ^ ((row >> 1) & 3)) * 8));
            int col = wn * 64 + i * 16 + (lane & 15);
            b[i] = ldbf8(Bs + col * 32 + (((lane >> 4) ^ ((col >> 1) & 3)) * 8));
        }
        #pragma unroll
        for (int i = 0; i < 4; ++i)
            #pragma unroll
            for (int j = 0; j < 4; ++j)
                acc[i][j] = __builtin_amdgcn_mfma_f32_16x16x32_bf16(a[i], b[j], acc[i][j], 0, 0, 0);
    }

    // Epilogue: permuted bf16 store to [B*H][T][64]
    #pragma unroll
    for (int j = 0; j < 4; ++j) {
        int n = n0 + wn * 64 + j * 16 + (lane & 15);
        int hh = n >> 6, dh = n & 63;
        #pragma unroll
        for (int i = 0; i < 4; ++i) {
            #pragma unroll
            for (int r = 0; r < 4; ++r) {
                int m = m0 + wm * 64 + i * 16 + (lane >> 4) * 4 + r;
                int bb = m >> 11, t = m & 2047;
                outp[((size_t)(bb * Hc + hh) * Tc + t) * 64 + dh] = f2bf(acc[i][j][r] * scale);
            }
        }
    }
}

// ---------------------------------------------------------------------------
// V transpose per bh: VT[bh][d][t] = V[bh][t][d]
// ---------------------------------------------------------------------------
__global__ __launch_bounds__(256)
void v_transpose_kernel(const u16* __restrict__ Vb, u16* __restrict__ VTb)
{
    __shared__ u16 Ts[64][68];
    const int tid = threadIdx.x;
    const int bh = blockIdx.y, t0 = blockIdx.x * 64;
    const size_t vbase = (size_t)bh * Tc * 64;
    #pragma unroll
    for (int it = 0; it < 4; ++it) {
        int flat = it * 1024 + tid * 4;
        int r = flat >> 6, c = flat & 63;
        *(ushort4*)&Ts[r][c] = *(const ushort4*)(Vb + vbase + (size_t)(t0 + r) * 64 + c);
    }
    __syncthreads();
    const size_t obase = (size_t)bh * 64 * Tc;
    #pragma unroll
    for (int it = 0; it < 4; ++it) {
        int flat = it * 1024 + tid * 4;
        int d = flat >> 6, tl = flat & 63;
        ushort4 o;
        o.x = Ts[tl][d]; o.y = Ts[tl + 1][d]; o.z = Ts[tl + 2][d]; o.w = Ts[tl + 3][d];
        *(ushort4*)(VTb + obase + (size_t)d * Tc + t0 + tl) = o;
    }
}

// ---------------------------------------------------------------------------
// MFMA flash attention (causal), swapped-QK^T, KVBLK=64 LDS-staged (R10-proven
// structure), exp2-domain softmax + defer-max + setprio. NEW: 1024-block
// heavy-first launch — id%8 = XCD keeps 8 bh per XCD (K/V L2-resident);
// qt = 15 - (j>>3) dispatches heavy q-tiles first so light blocks backfill
// (no tail), and 4 blocks/CU resident (LDS 34.8KB) doubles latency hiding.
// ---------------------------------------------------------------------------
__global__ __launch_bounds__(256)
void attn_mfma_kernel(const u16* __restrict__ Qb, const u16* __restrict__ Kb,
                      const u16* __restrict__ VTb, u16* __restrict__ ctxb)
{
    __shared__ __align__(16) u16 Ks[64 * 64];
    __shared__ __align__(16) u16 Vs[64 * 64];
    __shared__ __align__(16) u16 Ps[4][32 * 72];   // per-wave [q 0..31][kv 0..63] stride 72

    const int tid = threadIdx.x, lane = tid & 63, w = tid >> 6;
    const int g = lane >> 4, lq = lane & 15;
    const int id = blockIdx.x;
    const int xcd = id & 7, j = id >> 3;           // j: 0..127 per XCD
    const int bh = (xcd << 3) | (j & 7);           // 8 bh per XCD
    const int qt = 15 - (j >> 3);                  // heavy q-tiles dispatched first
    const size_t qkbase = (size_t)bh * Tc * 64;
    const size_t vtbase = (size_t)bh * 64 * Tc;
    const int b = bh >> 4, h = bh & 15;
    u16* pw = &Ps[w][0];

    const int q0 = qt * 128;
    const int nkt = qt * 2 + 2;                    // kv tiles for this q-tile

    // Q fragments (B-operand: col=q=lq, k=dh), pre-scaled by 0.125*log2e
    bf16x8 qf[2][2];
    #pragma unroll
    for (int qfi = 0; qfi < 2; ++qfi)
        #pragma unroll
        for (int kf = 0; kf < 2; ++kf) {
            int row = q0 + w * 32 + qfi * 16 + lq;
            qf[qfi][kf] = ldbf8(Qb + qkbase + (size_t)row * 64 + kf * 32 + g * 8);
        }

    f32x4 o_acc[2][4] = {};
    float m_run[2] = {-INFINITY, -INFINITY};
    float l_run[2] = {0.f, 0.f};

    for (int kt = 0; kt < nkt; ++kt) {
        const int kv0 = kt * 64;
        __syncthreads();
        // stage K (rows kv, cols dh) and VT (rows dh, cols t), swizzled src
        #pragma unroll
        for (int t = 0; t < 2; ++t) {
            int ci = w * 64 + t * 256 + lane;          // chunk 0..511
            int r = ci >> 3, p = ci & 7;
            int pc = p ^ (r & 7);
            gload_lds16(Kb + qkbase + (size_t)(kv0 + r) * 64 + pc * 8,
                        Ks + (size_t)(w * 64 + t * 256) * 8);
            gload_lds16(VTb + vtbase + (size_t)r * Tc + kv0 + pc * 8,
                        Vs + (size_t)(w * 64 + t * 256) * 8);
        }
        __syncthreads();

        // S^T = K Q^T: D[kv][q]  (4 kv-frags x 2 q-frags)
        f32x4 s[4][2] = {};
        __builtin_amdgcn_s_setprio(1);
        #pragma unroll
        for (int kf = 0; kf < 2; ++kf) {
            bf16x8 kb[4];
            #pragma unroll
            for (int ni = 0; ni < 4; ++ni) {
                int rr = ni * 16 + lq;
                int pc = (g + 4 * kf) ^ (rr & 7);
                kb[ni] = ldbf8(Ks + rr * 64 + pc * 8);
            }
            #pragma unroll
            for (int ni = 0; ni < 4; ++ni)
                #pragma unroll
                for (int qfi = 0; qfi < 2; ++qfi)
                    s[ni][qfi] = __builtin_amdgcn_mfma_f32_16x16x32_bf16(kb[ni], qf[qfi][kf], s[ni][qfi], 0, 0, 0);
        }
        __builtin_amdgcn_s_setprio(0);

        // causal mask: kv > q -> -inf (only last two tiles can straddle)
        if (kt >= nkt - 2) {
            #pragma unroll
            for (int ni = 0; ni < 4; ++ni)
                #pragma unroll
                for (int qfi = 0; qfi < 2; ++qfi)
                    #pragma unroll
                    for (int r = 0; r < 4; ++r) {
                        int kv = kv0 + ni * 16 + 4 * g + r;
                        int q  = q0 + w * 32 + qfi * 16 + lq;
                        if (kv > q) s[ni][qfi][r] = -INFINITY;
                    }
        }

        // online softmax (exp2 domain); defer-max: skip rescale if growth <= 12
        #pragma unroll
        for (int qfi = 0; qfi < 2; ++qfi) {
            float mrow = -INFINITY;
            #pragma unroll
            for (int ni = 0; ni < 4; ++ni)
                #pragma unroll
                for (int r = 0; r < 4; ++r) mrow = fmaxf(mrow, s[ni][qfi][r]);
            mrow = fmaxf(mrow, __shfl_xor(mrow, 16, 64));
            mrow = fmaxf(mrow, __shfl_xor(mrow, 32, 64));
            if (!__all(mrow <= m_run[qfi] + 12.0f)) {
                float mnew  = fmaxf(m_run[qfi], mrow);
                float alpha = fexp2(m_run[qfi] - mnew);   // exp2(-inf)=0 first tile
                m_run[qfi] = mnew;
                l_run[qfi] *= alpha;
                #pragma unroll
                for (int r = 0; r < 4; ++r) {
                    float ar = __shfl(alpha, 4 * g + r, 16);
                    #pragma unroll
                    for (int nd = 0; nd < 4; ++nd) o_acc[qfi][nd][r] *= ar;
                }
            }
            float mq = m_run[qfi];
            float sum = 0.f;
            #pragma unroll
            for (int ni = 0; ni < 4; ++ni)
                #pragma unroll
                for (int r = 0; r < 4; ++r) {
                    float pe = fexp2(s[ni][qfi][r] - mq);
                    s[ni][qfi][r] = pe;
                    sum += pe;
                }
            sum += __shfl_xor(sum, 16, 64);
            sum += __shfl_xor(sum, 32, 64);
            l_run[qfi] += sum;
        }

        // pack P -> per-wave LDS: row q_local, cols kv (stride 72 u16)
        #pragma unroll
        for (int qfi = 0; qfi < 2; ++qfi)
            #pragma unroll
            for (int ni = 0; ni < 4; ++ni) {
                float a0 = s[ni][qfi][0], a1 = s[ni][qfi][1];
                float a2 = s[ni][qfi][2], a3 = s[ni][qfi][3];
                uint32_t lo, hi;
                asm volatile("v_cvt_pk_bf16_f32 %0, %1, %2" : "=v"(lo) : "v"(a0), "v"(a1));
                asm volatile("v_cvt_pk_bf16_f32 %0, %1, %2" : "=v"(hi) : "v"(a2), "v"(a3));
                uint2 pk = make_uint2(lo, hi);
                *(uint2*)(pw + (qfi * 16 + lq) * 72 + ni * 16 + 4 * g) = pk;
            }

        // PV: o[q][dh] += P[q][kv] V[kv][dh]; A=P from LDS, B=VT tile
        bf16x8 pa[2][2];
        #pragma unroll
        for (int qfi = 0; qfi < 2; ++qfi)
            #pragma unroll
            for (int kf = 0; kf < 2; ++kf)
                pa[qfi][kf] = ldbf8(pw + (qfi * 16 + lq) * 72 + kf * 32 + 8 * g);
        __builtin_amdgcn_s_setprio(1);
        #pragma unroll
        for (int kf = 0; kf < 2; ++kf) {
            bf16x8 vb[4];
            #pragma unroll
            for (int nd = 0; nd < 4; ++nd) {
                int rr = nd * 16 + lq;
                int pc = (g + 4 * kf) ^ (rr & 7);
                vb[nd] = ldbf8(Vs + rr * 64 + pc * 8);
            }
            #pragma unroll
            for (int qfi = 0; qfi < 2; ++qfi)
                #pragma unroll
                for (int nd = 0; nd < 4; ++nd)
                    o_acc[qfi][nd] = __builtin_amdgcn_mfma_f32_16x16x32_bf16(pa[qfi][kf], vb[nd], o_acc[qfi][nd], 0, 0, 0);
        }
        __builtin_amdgcn_s_setprio(0);
    }

    // normalize + store ctx [B][T][D] bf16 (l held at lane lq==q)
    #pragma unroll
    for (int qfi = 0; qfi < 2; ++qfi)
        #pragma unroll
        for (int r = 0; r < 4; ++r) {
            float lr = __shfl(l_run[qfi], 4 * g + r, 16);
            float inv = 1.0f / lr;
            int qrow = q0 + w * 32 + qfi * 16 + 4 * g + r;
            #pragma unroll
            for (int nd = 0; nd < 4; ++nd) {
                int d = h * 64 + nd * 16 + lq;
                ctxb[(size_t)(b * Tc + qrow) * Dc + d] = f2bf(o_acc[qfi][nd][r] * inv);
            }
        }
}

// ---------------------------------------------------------------------------
// Output projection: out[8192][1024] = ctx @ Wo + bo   (f32 out)
// ---------------------------------------------------------------------------
__global__ __launch_bounds__(256)
void out_gemm_kernel(const u16* __restrict__ ctxb, const u16* __restrict__ WTo,
                     const float* __restrict__ bo, float* __restrict__ out)
{
    __shared__ __align__(16) u16 As[128 * 32];
    __shared__ __align__(16) u16 Bs[128 * 32];

    const int tid = threadIdx.x, lane = tid & 63, w = tid >> 6;
    const int wm = w >> 1, wn = w & 1;
    const int m0 = blockIdx.x * 128, n0 = blockIdx.y * 128;

    f32x4 acc[4][4] = {};

    for (int k0 = 0; k0 < Dc; k0 += 32) {
        __syncthreads();
        #pragma unroll
        for (int t = 0; t < 2; ++t) {
            int ci = w * 64 + t * 256 + lane;
            int r = ci >> 2, p = ci & 3;
            int pc = p ^ ((r >> 1) & 3);
            gload_lds16(ctxb + (size_t)(m0 + r) * Dc + k0 + pc * 8,
                        As + (size_t)(w * 64 + t * 256) * 8);
            gload_lds16(WTo + (size_t)(n0 + r) * Dc + k0 + pc * 8,
                        Bs + (size_t)(w * 64 + t * 256) * 8);
        }
        __syncthreads();

        bf16x8 a[4], b[4];
        #pragma unroll
        for (int i = 0; i < 4; ++i) {
            int row = wm * 64 + i * 16 + (lane & 15);
            a[i] = ldbf8(As + row * 32 + (((lane >> 4) ^ ((row >> 1) & 3)) * 8));
            int col = wn * 64 + i * 16 + (lane & 15);
            b[i] = ldbf8(Bs + col * 32 + (((lane >> 4) ^ ((col >> 1) & 3)) * 8));
        }
        #pragma unroll
        for (int i = 0; i < 4; ++i)
            #pragma unroll
            for (int j = 0; j < 4; ++j)
                acc[i][j] = __builtin_amdgcn_mfma_f32_16x16x32_bf16(a[i], b[j], acc[i][j], 0, 0, 0);
    }

    #pragma unroll
    for (int j = 0; j < 4; ++j) {
        int n = n0 + wn * 64 + j * 16 + (lane & 15);
        float bias = bo[n];
        #pragma unroll
        for (int i = 0; i < 4; ++i) {
            #pragma unroll
            for (int r = 0; r < 4; ++r) {
                int m = m0 + wm * 64 + i * 16 + (lane >> 4) * 4 + r;
                out[(size_t)m * Dc + n] = acc[i][j][r] + bias;
            }
        }
    }
}

// ---------------------------------------------------------------------------
extern "C" void kernel_launch(void* const* d_in, const int* in_sizes, int n_in,
                              void* d_out, int out_size, void* d_ws, size_t ws_size,
                              hipStream_t stream)
{
    const float* x  = (const float*)d_in[0];
    const float* Wq = (const float*)d_in[1];
    const float* Wk = (const float*)d_in[2];
    const float* Wv = (const float*)d_in[3];
    const float* Wo = (const float*)d_in[4];
    const float* bo = (const float*)d_in[5];
    float* out = (float*)d_out;

    u16* xb   = (u16*)d_ws;            // [8192][1024]
    u16* WTq  = xb + NQKV;             // [1024][1024] (n-major)
    u16* WTk  = WTq + NW;
    u16* WTv  = WTk + NW;
    u16* WTo  = WTv + NW;
    u16* Qb   = WTo + NW;              // [BH][T][64], pre-scaled by 0.125*log2e
    u16* Kb   = Qb + NQKV;
    u16* Vb   = Kb + NQKV;
    u16* VTb  = Vb + NQKV;             // [BH][64][T]
    u16* ctxb = VTb + NQKV;            // [B][T][D]

    cvt_x_kernel<<<8192, 256, 0, stream>>>(x, xb);
    wt_cvt_kernel<<<dim3(16, 16, 4), 256, 0, stream>>>(Wq, Wk, Wv, Wo, WTq, WTk, WTv, WTo);
    qkv_gemm_kernel<<<dim3(64, 8, 3), 256, 0, stream>>>(xb, WTq, WTk, WTv, Qb, Kb, Vb);
    v_transpose_kernel<<<dim3(32, 64), 256, 0, stream>>>(Vb, VTb);
    attn_mfma_kernel<<<dim3(1024), 256, 0, stream>>>(Qb, Kb, VTb, ctxb);
    out_gemm_kernel<<<dim3(64, 8), 256, 0, stream>>>(ctxb, WTo, bo, out);
}